// Round 12
// baseline (8578.550 us; speedup 1.0000x reference)
//
#include <hip/hip_runtime.h>
#include <math.h>

#define HDIM 1024
#define BDIM 64
#define TDIM 512
#define KIN  128
#define NBLK 128            // 1 octet (8 hidden cols) per block
#define NTHR 1024           // 16 waves
#define FRAME (HDIM * BDIM) // halfs per ring frame (4-deep rings)

typedef _Float16 f16;
typedef __attribute__((ext_vector_type(2))) _Float16 f16x2;
typedef __attribute__((ext_vector_type(8))) _Float16 f16x8;
typedef __attribute__((ext_vector_type(4))) float f32x4;
typedef __attribute__((ext_vector_type(4))) unsigned u32x4;

#define MFMA16(a, b, c) __builtin_amdgcn_mfma_f32_16x16x32_f16((a), (b), (c), 0, 0, 0)

__device__ __forceinline__ float sigm(float x) { return 1.0f / (1.0f + expf(-x)); }

// ---------------------------------------------------------------------------
// Octet ring layout (halfs): idx(k, m) = (k>>3)*512 + m*8 + (k&7).
// All ring I/O sc0sc1 (L3 coherence point, no cache-wide fences).
// ---------------------------------------------------------------------------
__device__ __forceinline__ f16x8 ld_cg(const f16* p) {
    f16x8 r;
    asm volatile("global_load_dwordx4 %0, %1, off sc0 sc1"
                 : "=v"(r) : "v"(p) : "memory");
    return r;
}
#define VM_WAIT8(r0, r1, r2, r3, r4, r5, r6, r7)                         \
    asm volatile("s_waitcnt vmcnt(0)"                                    \
                 : "+v"(r0), "+v"(r1), "+v"(r2), "+v"(r3),               \
                   "+v"(r4), "+v"(r5), "+v"(r6), "+v"(r7))

__device__ __forceinline__ void st_cg16(f16* p, u32x4 v) {
    asm volatile("global_store_dwordx4 %0, %1, off sc0 sc1"
                 :: "v"(p), "v"(v) : "memory");
}
#define VM_DRAIN() asm volatile("s_waitcnt vmcnt(0)" ::: "memory")

// ---------------------------------------------------------------------------
// Dataflow tags: tag[frame][oct] (16B stride) = published step + 2, monotone.
// Producer: data store -> vmcnt(0) -> tag store  (L3 orders them).
// Consumer wave: poll only the 2 octets each lane reads, then load.
// ---------------------------------------------------------------------------
__device__ __forceinline__ void tag_pub(unsigned* tags, int f, int oct, unsigned v) {
    __hip_atomic_store(tags + ((size_t)f * 128 + oct) * 4, v,
                       __ATOMIC_RELAXED, __HIP_MEMORY_SCOPE_AGENT);
}
__device__ __forceinline__ void poll2(const unsigned* tags, int f, int o0, int o1,
                                      unsigned tgt) {
    const unsigned* p0 = tags + ((size_t)f * 128 + o0) * 4;
    const unsigned* p1 = tags + ((size_t)f * 128 + o1) * 4;
    for (;;) {
        unsigned t0 = __hip_atomic_load(p0, __ATOMIC_RELAXED,
                                        __HIP_MEMORY_SCOPE_AGENT);
        unsigned t1 = __hip_atomic_load(p1, __ATOMIC_RELAXED,
                                        __HIP_MEMORY_SCOPE_AGENT);
        if (!__any((t0 < tgt) || (t1 < tgt))) break;
        __builtin_amdgcn_s_sleep(1);
    }
}

// ---------------------------------------------------------------------------
__global__ void cvt_w(const float* __restrict__ src, f16* __restrict__ dst, int n2) {
    int i = blockIdx.x * blockDim.x + threadIdx.x;
    if (i < n2) {
        float2 a = ((const float2*)src)[i];
        f16x2 o = {(f16)a.x, (f16)a.y};
        ((f16x2*)dst)[i] = o;
    }
}

// x[b][t][k] fp32 -> xP[t][b][k] fp16
__global__ void cvt_x(const float* __restrict__ x, f16* __restrict__ xP) {
    int P = blockIdx.x * blockDim.x + threadIdx.x;    // pair index
    if (P >= TDIM * BDIM * (KIN / 2)) return;
    int kp = P & 63;
    int b  = (P >> 6) & 63;
    int t  = P >> 12;
    float2 v = ((const float2*)x)[((size_t)b * TDIM + t) * (KIN / 2) + kp];
    f16x2 o = {(f16)v.x, (f16)v.y};
    ((f16x2*)xP)[((size_t)t * BDIM + b) * (KIN / 2) + kp] = o;
}

// ---------------------------------------------------------------------------
// Fused 2-layer LSTM, tag-dataflow (no global barrier).
// 128 blocks x 16 waves; block owns 1 octet (8 cols, 2 MFMA n-tiles) of BOTH
// layers. Wave w: K-slice [w*64,(w+1)*64). Superstep s = layer1 step s +
// layer2 step s-1 (r9's pipeline offset).
// Tags: h1^{(t)} -> tag1[t&3]=t+2 (published mid-body of superstep t);
//       h2^{(t)} -> tag2[t&3]=t+2 (published end of superstep t+1).
// Owners: waves 0..7 = layer1 cols (c1), waves 8..15 = layer2 cols (c2).
// Publishers: wave 8 -> h1 (mid-body), wave 9 -> h2 (end).
// ---------------------------------------------------------------------------
__global__ void __launch_bounds__(NTHR, 1) lstm_fused(
    const f16* __restrict__ xP,
    const f16* __restrict__ Wc0, const f16* __restrict__ Wh0,
    const float* __restrict__ bih0, const float* __restrict__ bhh0,
    const f16* __restrict__ Wc1, const f16* __restrict__ Wh1,
    const float* __restrict__ bih1, const float* __restrict__ bhh1,
    f16* ring1, f16* ring2, unsigned* tag1, unsigned* tag2) {

    // red group ((nt*4+p)*4+mt)*324 + n*20 + quad*4 : 32 groups, 41.5 KB
    __shared__ float red[32 * 324 + 16];
    __shared__ __align__(16) f16 hbuf1[BDIM * 8];
    __shared__ __align__(16) f16 hbuf2[BDIM * 8];

    const int tid  = threadIdx.x;
    const int lane = tid & 63;
    const int w    = __builtin_amdgcn_readfirstlane(tid >> 6);   // 0..15
    const int oct  = __builtin_amdgcn_readfirstlane((int)blockIdx.x);
    const int iu8  = oct * 8;

    const int n    = lane & 15;
    const int quad = lane >> 4;
    const int am   = lane & 15;
    const int m    = lane;

    const int o0 = w * 8 + quad;       // octet of k-step j=0
    const int o1 = w * 8 + 4 + quad;   // octet of k-step j=1

    const int wr0 = iu8 + (n >> 2) + (n & 3) * HDIM;
    const int wr1 = wr0 + 4;

    // ---- stationary weight fragments (K-slice 64 per wave, 2 ksteps) ----
    f16x8 B1h[2][2], B2i[2][2], B2h[2][2], B1x[2];
    #pragma unroll
    for (int j = 0; j < 2; ++j) {
        const int ks = w * 64 + j * 32 + quad * 8;
        B1h[j][0] = *(const f16x8*)(Wh0 + (size_t)wr0 * HDIM + ks);
        B1h[j][1] = *(const f16x8*)(Wh0 + (size_t)wr1 * HDIM + ks);
        B2i[j][0] = *(const f16x8*)(Wc1 + (size_t)wr0 * HDIM + ks);
        B2i[j][1] = *(const f16x8*)(Wc1 + (size_t)wr1 * HDIM + ks);
        B2h[j][0] = *(const f16x8*)(Wh1 + (size_t)wr0 * HDIM + ks);
        B2h[j][1] = *(const f16x8*)(Wh1 + (size_t)wr1 * HDIM + ks);
    }
    if (w < 4) {
        const int kx = w * 32 + quad * 8;
        B1x[0] = *(const f16x8*)(Wc0 + (size_t)wr0 * KIN + kx);
        B1x[1] = *(const f16x8*)(Wc0 + (size_t)wr1 * KIN + kx);
    }

    // ---- owner state: w0-7 layer1 col iu8+w; w8-15 layer2 col iu8+w-8 ----
    const int il = w & 7;
    const int icol = iu8 + il;
    float bias[4];
    float c = 0.f;
    {
        const float* bi = (w < 8) ? bih0 : bih1;
        const float* bh = (w < 8) ? bhh0 : bhh1;
        #pragma unroll
        for (int g = 0; g < 4; ++g)
            bias[g] = bi[icol + g * HDIM] + bh[icol + g * HDIM];
    }

    // ---- init: h^{(-1)} = 0 in frame 3, tag value 1 ----
    if (w == 8) {
        st_cg16(ring1 + 3 * (size_t)FRAME + oct * 512 + lane * 8,
                (u32x4){0u, 0u, 0u, 0u});
        VM_DRAIN();
        if (lane == 0) tag_pub(tag1, 3, oct, 1u);
    }
    if (w == 9) {
        st_cg16(ring2 + 3 * (size_t)FRAME + oct * 512 + lane * 8,
                (u32x4){0u, 0u, 0u, 0u});
        VM_DRAIN();
        if (lane == 0) tag_pub(tag2, 3, oct, 1u);
    }

    const int p = w & 3;

    for (int s = 0; s <= TDIM; ++s) {
        // ---- wait h1^{(s-1)} per-wave (frame (s+3)&3, tag s+1) ----
        const int f1r = (s + 3) & 3;
        poll2(tag1, f1r, o0, o1, (unsigned)(s + 1));
        const f16* r1p = ring1 + (size_t)f1r * FRAME;

        // ---- A1 fragments + x ----
        f16x8 A[2][4];
        #pragma unroll
        for (int j = 0; j < 2; ++j) {
            const int ok = w * 8 + j * 4 + quad;
            #pragma unroll
            for (int mt = 0; mt < 4; ++mt)
                A[j][mt] = ld_cg(r1p + ok * 512 + (mt * 16 + am) * 8);
        }
        f16x8 ax[4];
        if (w < 4) {
            const int ts = (s < TDIM) ? s : (TDIM - 1);
            const f16* xb = xP + (size_t)ts * BDIM * KIN;
            const int kx = w * 32 + quad * 8;
            #pragma unroll
            for (int mt = 0; mt < 4; ++mt)
                ax[mt] = *(const f16x8*)(xb + (size_t)(mt * 16 + am) * KIN + kx);
        }
        VM_WAIT8(A[0][0], A[0][1], A[0][2], A[0][3],
                 A[1][0], A[1][1], A[1][2], A[1][3]);

        // ---- phase 1 MFMA: layer1 (B1h,+x) and layer2-Wih1 (B2i) ----
        f32x4 acc[2][4], acc2[2][4];
        #pragma unroll
        for (int nt = 0; nt < 2; ++nt)
            #pragma unroll
            for (int mt = 0; mt < 4; ++mt) {
                acc[nt][mt]  = (f32x4){0.f, 0.f, 0.f, 0.f};
                acc2[nt][mt] = (f32x4){0.f, 0.f, 0.f, 0.f};
            }
        #pragma unroll
        for (int j = 0; j < 2; ++j)
            #pragma unroll
            for (int nt = 0; nt < 2; ++nt)
                #pragma unroll
                for (int mt = 0; mt < 4; ++mt) {
                    acc[nt][mt]  = MFMA16(A[j][mt], B1h[j][nt], acc[nt][mt]);
                    acc2[nt][mt] = MFMA16(A[j][mt], B2i[j][nt], acc2[nt][mt]);
                }
        if (w < 4) {
            #pragma unroll
            for (int nt = 0; nt < 2; ++nt)
                #pragma unroll
                for (int mt = 0; mt < 4; ++mt)
                    acc[nt][mt] = MFMA16(ax[mt], B1x[nt], acc[nt][mt]);
        }

        // ---- fold1 (4-deep) ----
        if (w < 4) {
            #pragma unroll
            for (int nt = 0; nt < 2; ++nt)
                #pragma unroll
                for (int mt = 0; mt < 4; ++mt)
                    *(f32x4*)&red[((nt * 4 + p) * 4 + mt) * 324 + n * 20 + quad * 4] = acc[nt][mt];
        }
        __syncthreads();
        if (w >= 4 && w < 8) {
            #pragma unroll
            for (int nt = 0; nt < 2; ++nt)
                #pragma unroll
                for (int mt = 0; mt < 4; ++mt) {
                    float* a = &red[((nt * 4 + p) * 4 + mt) * 324 + n * 20 + quad * 4];
                    *(f32x4*)a = *(f32x4*)a + acc[nt][mt];
                }
        }
        __syncthreads();
        if (w >= 8 && w < 12) {
            #pragma unroll
            for (int nt = 0; nt < 2; ++nt)
                #pragma unroll
                for (int mt = 0; mt < 4; ++mt) {
                    float* a = &red[((nt * 4 + p) * 4 + mt) * 324 + n * 20 + quad * 4];
                    *(f32x4*)a = *(f32x4*)a + acc[nt][mt];
                }
        }
        __syncthreads();
        if (w >= 12) {
            #pragma unroll
            for (int nt = 0; nt < 2; ++nt)
                #pragma unroll
                for (int mt = 0; mt < 4; ++mt) {
                    float* a = &red[((nt * 4 + p) * 4 + mt) * 324 + n * 20 + quad * 4];
                    *(f32x4*)a = *(f32x4*)a + acc[nt][mt];
                }
        }
        __syncthreads();

        // ---- owners1 (w0-7): gates -> c1 -> hbuf1 ----
        if (w < 8 && s < TDIM) {
            const int ntl = il >> 2, cl = il & 3;
            const int mtm = m >> 4, qm = m & 15;
            float g4[4];
            #pragma unroll
            for (int g = 0; g < 4; ++g) {
                float sum = bias[g];
                #pragma unroll
                for (int pp = 0; pp < 4; ++pp)
                    sum += red[((ntl * 4 + pp) * 4 + mtm) * 324 + (cl * 4 + g) * 20 + qm];
                g4[g] = sum;
            }
            float ig = sigm(g4[0]), fg = sigm(g4[1]);
            float gg = tanhf(g4[2]), og = sigm(g4[3]);
            c = fg * c + ig * gg;
            hbuf1[m * 8 + il] = (f16)(og * tanhf(c));
        }
        __syncthreads();   // hbuf1 ready; red free for fold2

        // ---- publish h1^{(s)} mid-body (wave 8) ----
        if (w == 8 && s < TDIM) {
            u32x4 v = *(const u32x4*)&hbuf1[lane * 8];
            st_cg16(ring1 + (size_t)(s & 3) * FRAME + oct * 512 + lane * 8, v);
            VM_DRAIN();
            if (lane == 0) tag_pub(tag1, s & 3, oct, (unsigned)(s + 2));
        }

        // ---- wait h2^{(s-2)} (frame (s+2)&3, tag s) + A2 + phase 2 ----
        const int f2r = (s + 2) & 3;
        poll2(tag2, f2r, o0, o1, (unsigned)s);
        const f16* r2p = ring2 + (size_t)f2r * FRAME;
        #pragma unroll
        for (int j = 0; j < 2; ++j) {
            const int ok = w * 8 + j * 4 + quad;
            #pragma unroll
            for (int mt = 0; mt < 4; ++mt)
                A[j][mt] = ld_cg(r2p + ok * 512 + (mt * 16 + am) * 8);
        }
        VM_WAIT8(A[0][0], A[0][1], A[0][2], A[0][3],
                 A[1][0], A[1][1], A[1][2], A[1][3]);
        #pragma unroll
        for (int j = 0; j < 2; ++j)
            #pragma unroll
            for (int nt = 0; nt < 2; ++nt)
                #pragma unroll
                for (int mt = 0; mt < 4; ++mt)
                    acc2[nt][mt] = MFMA16(A[j][mt], B2h[j][nt], acc2[nt][mt]);

        // ---- fold2 (4-deep) ----
        if (w < 4) {
            #pragma unroll
            for (int nt = 0; nt < 2; ++nt)
                #pragma unroll
                for (int mt = 0; mt < 4; ++mt)
                    *(f32x4*)&red[((nt * 4 + p) * 4 + mt) * 324 + n * 20 + quad * 4] = acc2[nt][mt];
        }
        __syncthreads();
        if (w >= 4 && w < 8) {
            #pragma unroll
            for (int nt = 0; nt < 2; ++nt)
                #pragma unroll
                for (int mt = 0; mt < 4; ++mt) {
                    float* a = &red[((nt * 4 + p) * 4 + mt) * 324 + n * 20 + quad * 4];
                    *(f32x4*)a = *(f32x4*)a + acc2[nt][mt];
                }
        }
        __syncthreads();
        if (w >= 8 && w < 12) {
            #pragma unroll
            for (int nt = 0; nt < 2; ++nt)
                #pragma unroll
                for (int mt = 0; mt < 4; ++mt) {
                    float* a = &red[((nt * 4 + p) * 4 + mt) * 324 + n * 20 + quad * 4];
                    *(f32x4*)a = *(f32x4*)a + acc2[nt][mt];
                }
        }
        __syncthreads();
        if (w >= 12) {
            #pragma unroll
            for (int nt = 0; nt < 2; ++nt)
                #pragma unroll
                for (int mt = 0; mt < 4; ++mt) {
                    float* a = &red[((nt * 4 + p) * 4 + mt) * 324 + n * 20 + quad * 4];
                    *(f32x4*)a = *(f32x4*)a + acc2[nt][mt];
                }
        }
        __syncthreads();

        // ---- owners2 (w8-15): gates -> c2 -> hbuf2 ----
        if (w >= 8 && s >= 1) {
            const int ntl = il >> 2, cl = il & 3;
            const int mtm = m >> 4, qm = m & 15;
            float g4[4];
            #pragma unroll
            for (int g = 0; g < 4; ++g) {
                float sum = bias[g];
                #pragma unroll
                for (int pp = 0; pp < 4; ++pp)
                    sum += red[((ntl * 4 + pp) * 4 + mtm) * 324 + (cl * 4 + g) * 20 + qm];
                g4[g] = sum;
            }
            float ig = sigm(g4[0]), fg = sigm(g4[1]);
            float gg = tanhf(g4[2]), og = sigm(g4[3]);
            c = fg * c + ig * gg;
            hbuf2[m * 8 + il] = (f16)(og * tanhf(c));
        }
        __syncthreads();   // hbuf2 ready; also gates red reuse next superstep

        // ---- publish h2^{(s-1)} (wave 9) ----
        if (w == 9 && s >= 1) {
            u32x4 v = *(const u32x4*)&hbuf2[lane * 8];
            st_cg16(ring2 + (size_t)((s - 1) & 3) * FRAME + oct * 512 + lane * 8, v);
            VM_DRAIN();
            if (lane == 0) tag_pub(tag2, (s - 1) & 3, oct, (unsigned)(s + 1));
        }
    }
    // final h2^{(511)} is in ring2 frame 3
}

// ---------------------------------------------------------------------------
// out[b] = dot(h2[b, :], fc_w) + fc_b.  h2 in octet layout.
// ---------------------------------------------------------------------------
__global__ void fc_kernel(const f16* __restrict__ h2f,
                          const float* __restrict__ fcw,
                          const float* __restrict__ fcb,
                          float* __restrict__ out) {
    __shared__ float red[256];
    const int tid = threadIdx.x;
    const int b = tid >> 2, q = tid & 3;
    float s = 0.f;
    for (int oct = q * 32; oct < (q + 1) * 32; ++oct) {
        f16x8 v = *(const f16x8*)(h2f + oct * 512 + b * 8);
        #pragma unroll
        for (int j = 0; j < 8; ++j)
            s = fmaf((float)v[j], fcw[oct * 8 + j], s);
    }
    red[tid] = s;
    __syncthreads();
    if (q == 0)
        out[b] = red[tid] + red[tid + 1] + red[tid + 2] + red[tid + 3] + fcb[0];
}

// ---------------------------------------------------------------------------
extern "C" void kernel_launch(void* const* d_in, const int* in_sizes, int n_in,
                              void* d_out, int out_size, void* d_ws, size_t ws_size,
                              hipStream_t stream) {
    const float* x    = (const float*)d_in[0];
    const float* Wih0 = (const float*)d_in[1];
    const float* Whh0 = (const float*)d_in[2];
    const float* bih0 = (const float*)d_in[3];
    const float* bhh0 = (const float*)d_in[4];
    const float* Wih1 = (const float*)d_in[5];
    const float* Whh1 = (const float*)d_in[6];
    const float* bih1 = (const float*)d_in[7];
    const float* bhh1 = (const float*)d_in[8];
    const float* fcw  = (const float*)d_in[9];
    const float* fcb  = (const float*)d_in[10];
    float* out = (float*)d_out;

    // workspace (halfs): xP | Wc0 | Wh0 | Wc1 | Wh1 | ring1[4F] | ring2[4F] | tags
    f16* xPd   = (f16*)d_ws;
    f16* Wc0   = xPd + (size_t)TDIM * BDIM * KIN;
    f16* Wh0   = Wc0 + (size_t)4 * HDIM * KIN;
    f16* Wc1   = Wh0 + (size_t)4 * HDIM * HDIM;
    f16* Wh1   = Wc1 + (size_t)4 * HDIM * HDIM;
    f16* ring1 = Wh1 + (size_t)4 * HDIM * HDIM;
    f16* ring2 = ring1 + 4 * (size_t)FRAME;
    unsigned* tag1 = (unsigned*)(ring2 + 4 * (size_t)FRAME);
    unsigned* tag2 = tag1 + 4 * 128 * 4;

    hipMemsetAsync(tag1, 0, 2 * 4 * 128 * 4 * sizeof(unsigned), stream);
    {
        int n2 = 4 * HDIM * KIN / 2;
        cvt_w<<<dim3((n2 + 255) / 256), dim3(256), 0, stream>>>(Wih0, Wc0, n2);
        n2 = 4 * HDIM * HDIM / 2;
        cvt_w<<<dim3((n2 + 255) / 256), dim3(256), 0, stream>>>(Whh0, Wh0, n2);
        cvt_w<<<dim3((n2 + 255) / 256), dim3(256), 0, stream>>>(Whh1, Wh1, n2);
        cvt_w<<<dim3((n2 + 255) / 256), dim3(256), 0, stream>>>(Wih1, Wc1, n2);
    }
    {
        int np = TDIM * BDIM * (KIN / 2);
        cvt_x<<<dim3((np + 255) / 256), dim3(256), 0, stream>>>(x, xPd);
    }

    void* args[13];
    args[0]  = (void*)&xPd;
    args[1]  = (void*)&Wc0;
    args[2]  = (void*)&Wh0;
    args[3]  = (void*)&bih0;
    args[4]  = (void*)&bhh0;
    args[5]  = (void*)&Wc1;
    args[6]  = (void*)&Wh1;
    args[7]  = (void*)&bih1;
    args[8]  = (void*)&bhh1;
    args[9]  = (void*)&ring1;
    args[10] = (void*)&ring2;
    args[11] = (void*)&tag1;
    args[12] = (void*)&tag2;
    hipLaunchCooperativeKernel(reinterpret_cast<void*>(lstm_fused), dim3(NBLK), dim3(NTHR),
                               args, 0, stream);

    fc_kernel<<<dim3(1), dim3(256), 0, stream>>>(ring2 + 3 * (size_t)FRAME, fcw, fcb, out);
}

// Round 13
// 3034.192 us; speedup vs baseline: 2.8273x; 2.8273x over previous
//
#include <hip/hip_runtime.h>
#include <math.h>

#define HDIM 1024
#define BDIM 64
#define TDIM 512
#define KIN  128
#define NBLK 256
#define NTHR 1024           // 16 waves
#define FRAME (HDIM * BDIM) // halfs per ring frame (2-deep rings, as r9)

typedef _Float16 f16;
typedef __attribute__((ext_vector_type(2))) _Float16 f16x2;
typedef __attribute__((ext_vector_type(8))) _Float16 f16x8;
typedef __attribute__((ext_vector_type(4))) float f32x4;
typedef __attribute__((ext_vector_type(4))) unsigned u32x4;

#define MFMA16(a, b, c) __builtin_amdgcn_mfma_f32_16x16x32_f16((a), (b), (c), 0, 0, 0)

__device__ __forceinline__ float sigm(float x) { return 1.0f / (1.0f + expf(-x)); }

// ---------------------------------------------------------------------------
// Octet ring layout (halfs): idx(k, m) = (k>>3)*512 + m*8 + (k&7).
// A-frag load = one dwordx4/lane; h-store = one dwordx2 wave-store per block.
// All ring I/O sc0sc1 (L3 coherence point, fence-free).
// ---------------------------------------------------------------------------
__device__ __forceinline__ f16x8 ld_cg(const f16* p) {
    f16x8 r;
    asm volatile("global_load_dwordx4 %0, %1, off sc0 sc1"
                 : "=v"(r) : "v"(p) : "memory");
    return r;
}
#define VM_WAIT8(r0, r1, r2, r3, r4, r5, r6, r7)                         \
    asm volatile("s_waitcnt vmcnt(0)"                                    \
                 : "+v"(r0), "+v"(r1), "+v"(r2), "+v"(r3),               \
                   "+v"(r4), "+v"(r5), "+v"(r6), "+v"(r7))

__device__ __forceinline__ void st_cg8(f16* p, uint2 v) {
    asm volatile("global_store_dwordx2 %0, %1, off sc0 sc1"
                 :: "v"(p), "v"(v) : "memory");
}
#define VM_DRAIN() asm volatile("s_waitcnt vmcnt(0)" ::: "memory")

// ---------------------------------------------------------------------------
// Tag sync: tag[bid] (4B, contiguous 1KB array per ring) = published step
// tag value, monotone, plain sc0sc1 store by producer lane0 (no atomic RMW,
// no contention). Poller = one full wave: 64 lanes x dwordx4 = all 256 tags
// in ONE coalesced 1KB read per poll round; exit when min >= target.
// ---------------------------------------------------------------------------
__device__ __forceinline__ void tag_pub(unsigned* tag, unsigned v) {
    asm volatile("global_store_dword %0, %1, off sc0 sc1"
                 :: "v"(tag), "v"(v) : "memory");
}
__device__ __forceinline__ void tag_poll(const unsigned* tags, int lane,
                                         unsigned tgt) {
    const unsigned* p = tags + lane * 4;
    for (;;) {
        u32x4 t;
        asm volatile("global_load_dwordx4 %0, %1, off sc0 sc1\n\t"
                     "s_waitcnt vmcnt(0)"
                     : "=v"(t) : "v"(p) : "memory");
        bool ok = (t.x >= tgt) && (t.y >= tgt) && (t.z >= tgt) && (t.w >= tgt);
        if (__all(ok)) break;
        __builtin_amdgcn_s_sleep(1);
    }
}

// ---------------------------------------------------------------------------
__global__ void cvt_w(const float* __restrict__ src, f16* __restrict__ dst, int n2) {
    int i = blockIdx.x * blockDim.x + threadIdx.x;
    if (i < n2) {
        float2 a = ((const float2*)src)[i];
        f16x2 o = {(f16)a.x, (f16)a.y};
        ((f16x2*)dst)[i] = o;
    }
}

// x[b][t][k] fp32 -> xP[t][b][k] fp16
__global__ void cvt_x(const float* __restrict__ x, f16* __restrict__ xP) {
    int P = blockIdx.x * blockDim.x + threadIdx.x;    // pair index
    if (P >= TDIM * BDIM * (KIN / 2)) return;
    int kp = P & 63;
    int b  = (P >> 6) & 63;
    int t  = P >> 12;
    float2 v = ((const float2*)x)[((size_t)b * TDIM + t) * (KIN / 2) + kp];
    f16x2 o = {(f16)v.x, (f16)v.y};
    ((f16x2*)xP)[((size_t)t * BDIM + b) * (KIN / 2) + kp] = o;
}

// ---------------------------------------------------------------------------
// Fused 2-layer LSTM — r9's exact compute/pipeline structure (256 blocks x
// 16 waves, 4 cols/block, octet layout, 2-deep rings, LDS-staged coalesced
// publishes). Single change vs r9: flat-8 atomic barrier -> per-block tag
// stores + wave-parallel coalesced tag polls (wave 0 polls tagA at top,
// wave 15 polls tagB during reduce1 window).
// Tag convention: after publishing h1^{(t)}: tagA[bid] = t+2 (init t=-1 -> 1);
//                 after publishing h2^{(t)}: tagB[bid] = t+2.
// Waits: top of s needs h1^{(s-1)} -> tagA >= s+1;
//        mid-body needs h2^{(s-2)} -> tagB >= s.
// ---------------------------------------------------------------------------
__global__ void __launch_bounds__(NTHR, 4) lstm_fused(
    const f16* __restrict__ xP,
    const f16* __restrict__ Wc0, const f16* __restrict__ Wh0,
    const float* __restrict__ bih0, const float* __restrict__ bhh0,
    const f16* __restrict__ Wc1, const f16* __restrict__ Wh1,
    const float* __restrict__ bih1, const float* __restrict__ bhh1,
    f16* ring1, f16* ring2, unsigned* tagA, unsigned* tagB) {

    __shared__ float red[32 * 324 + 16];          // ~41.6 KB padded slots
    __shared__ __align__(16) f16 hbuf1[BDIM * 4]; // owner h1 staging
    __shared__ __align__(16) f16 hbuf2[BDIM * 4];

    const int tid  = threadIdx.x;
    const int lane = tid & 63;
    const int w    = __builtin_amdgcn_readfirstlane(tid >> 6);   // 0..15
    const int bid  = (int)blockIdx.x;
    const int iu4  = __builtin_amdgcn_readfirstlane(bid * 4);

    const int n    = lane & 15;
    const int quad = lane >> 4;
    const int am   = lane & 15;
    const int wrow = iu4 + (n >> 2) + (n & 3) * HDIM;

    // block's h region in octet layout
    const int oct4 = iu4 >> 3;        // octet index of block's 4 cols
    const int coff = iu4 & 7;         // 0 or 4 within octet

    // ---- preload stationary weight fragments ----
    f16x8 B1x;
    f16x8 B1h[2], B2i[2], B2h[2];
    {
        const int kq = quad * 8;
        if (w < 4)
            B1x = *(const f16x8*)(Wc0 + (size_t)wrow * KIN + w * 32 + kq);
        #pragma unroll
        for (int j = 0; j < 2; ++j) {
            const int ks = (2 * w + j) * 32 + kq;
            B1h[j] = *(const f16x8*)(Wh0 + (size_t)wrow * HDIM + ks);
            B2i[j] = *(const f16x8*)(Wc1 + (size_t)wrow * HDIM + ks);
            B2h[j] = *(const f16x8*)(Wh1 + (size_t)wrow * HDIM + ks);
        }
    }

    // ---- owner state (waves 0..3: col icol = iu4 + w, batch = lane) ----
    float bias1[4], bias2[4];
    float c1 = 0.f, c2 = 0.f;
    const int il = w;
    const int m  = lane;
    if (w < 4) {
        const int i = iu4 + il;
        #pragma unroll
        for (int g = 0; g < 4; ++g) {
            bias1[g] = bih0[i + g * HDIM] + bhh0[i + g * HDIM];
            bias2[g] = bih1[i + g * HDIM] + bhh1[i + g * HDIM];
        }
    }

    // ---- init: zero h^{(-1)} (frame 1) via coalesced stores + tag=1 ----
    if (w == 8) {
        uint2 z = {0u, 0u};
        st_cg8(ring1 + FRAME + oct4 * 512 + lane * 8 + coff, z);
        VM_DRAIN();
        if (lane == 0) tag_pub(tagA + bid, 1u);
    }
    if (w == 9) {
        uint2 z = {0u, 0u};
        st_cg8(ring2 + FRAME + oct4 * 512 + lane * 8 + coff, z);
        VM_DRAIN();
        if (lane == 0) tag_pub(tagB + bid, 1u);
    }

    for (int s = 0; s <= TDIM; ++s) {
        const f16* r1p = ring1 + (size_t)((s + 1) & 1) * FRAME;  // h1^{(s-1)}
        const f16* r2p = ring2 + (size_t)(s & 1) * FRAME;        // h2^{(s-2)}

        // ---- wait for h1^{(s-1)}: wave 0 polls all 256 tags in one read ----
        if (w == 0) tag_poll(tagA, lane, (unsigned)(s + 1));
        __syncthreads();   // S1 (also protects red/hbuf reuse from prev iter)

        // ---- A1 fragments (octet layout: one dwordx4 each) ----
        f16x8 A1[2][4];
        #pragma unroll
        for (int j = 0; j < 2; ++j) {
            const int oct = (2 * w + j) * 4 + quad;
            #pragma unroll
            for (int mt = 0; mt < 4; ++mt)
                A1[j][mt] = ld_cg(r1p + oct * 512 + (mt * 16 + am) * 8);
        }
        VM_WAIT8(A1[0][0], A1[0][1], A1[0][2], A1[0][3],
                 A1[1][0], A1[1][1], A1[1][2], A1[1][3]);

        // ---- phase 1 (layer1) + layer2-Wih1 part (both consume A1) ----
        f32x4 acc[4], acc2[4];
        #pragma unroll
        for (int mt = 0; mt < 4; ++mt) {
            acc[mt]  = (f32x4){0.f, 0.f, 0.f, 0.f};
            acc2[mt] = (f32x4){0.f, 0.f, 0.f, 0.f};
        }
        #pragma unroll
        for (int j = 0; j < 2; ++j)
            #pragma unroll
            for (int mt = 0; mt < 4; ++mt) {
                acc[mt]  = MFMA16(A1[j][mt], B1h[j], acc[mt]);
                acc2[mt] = MFMA16(A1[j][mt], B2i[j], acc2[mt]);
            }
        if (w < 4) {
            const int ts = (s < TDIM) ? s : (TDIM - 1);
            const f16* xb = xP + (size_t)ts * BDIM * KIN;
            const int kx = w * 32 + quad * 8;
            #pragma unroll
            for (int mt = 0; mt < 4; ++mt) {
                f16x8 ax = *(const f16x8*)(xb + (size_t)(mt * 16 + am) * KIN + kx);
                acc[mt] = MFMA16(ax, B1x, acc[mt]);
            }
        }

        // ---- phase-1 reduction (8 partials) ----
        const int p = w & 7;
        if (w < 8) {
            #pragma unroll
            for (int mt = 0; mt < 4; ++mt)
                *(f32x4*)&red[(p * 4 + mt) * 324 + n * 20 + quad * 4] = acc[mt];
        }
        __syncthreads();   // S2
        if (w >= 8) {
            #pragma unroll
            for (int mt = 0; mt < 4; ++mt) {
                float* a = &red[(p * 4 + mt) * 324 + n * 20 + quad * 4];
                f32x4 v = *(f32x4*)a;
                *(f32x4*)a = v + acc[mt];
            }
        }
        __syncthreads();   // S3

        // ---- reduce1: owners -> h1 into LDS; wave 15 polls tagB ----
        if (w < 4 && s < TDIM) {
            const int mt = m >> 4, qm = m & 15;
            float g4[4];
            #pragma unroll
            for (int g = 0; g < 4; ++g) {
                float sum = bias1[g];
                #pragma unroll
                for (int pp = 0; pp < 8; ++pp)
                    sum += red[(pp * 4 + mt) * 324 + (il * 4 + g) * 20 + qm];
                g4[g] = sum;
            }
            float ig = sigm(g4[0]), fg = sigm(g4[1]);
            float gg = tanhf(g4[2]), og = sigm(g4[3]);
            c1 = fg * c1 + ig * gg;
            hbuf1[m * 4 + il] = (f16)(og * tanhf(c1));
        }
        // wait for h2^{(s-2)} (published end of superstep s-1 -> usually free)
        if (w == 15) tag_poll(tagB, lane, (unsigned)s);
        __syncthreads();   // S4: hbuf1 ready, tagB satisfied, red free

        // ---- wave 8: coalesced h1 store + tag publish (mid-iteration) ----
        if (w == 8 && s < TDIM) {
            uint2 v = *(const uint2*)&hbuf1[lane * 4];
            st_cg8(ring1 + (size_t)(s & 1) * FRAME + oct4 * 512 + lane * 8 + coff, v);
            VM_DRAIN();
            if (lane == 0) tag_pub(tagA + bid, (unsigned)(s + 2));
        }

        // ---- A2 fragments of h2^{(s-2)} ----
        f16x8 A2[2][4];
        #pragma unroll
        for (int j = 0; j < 2; ++j) {
            const int oct = (2 * w + j) * 4 + quad;
            #pragma unroll
            for (int mt = 0; mt < 4; ++mt)
                A2[j][mt] = ld_cg(r2p + oct * 512 + (mt * 16 + am) * 8);
        }
        VM_WAIT8(A2[0][0], A2[0][1], A2[0][2], A2[0][3],
                 A2[1][0], A2[1][1], A2[1][2], A2[1][3]);
        #pragma unroll
        for (int j = 0; j < 2; ++j)
            #pragma unroll
            for (int mt = 0; mt < 4; ++mt)
                acc2[mt] = MFMA16(A2[j][mt], B2h[j], acc2[mt]);

        // ---- phase-2 reduction ----
        if (w < 8) {
            #pragma unroll
            for (int mt = 0; mt < 4; ++mt)
                *(f32x4*)&red[(p * 4 + mt) * 324 + n * 20 + quad * 4] = acc2[mt];
        }
        __syncthreads();   // S5
        if (w >= 8) {
            #pragma unroll
            for (int mt = 0; mt < 4; ++mt) {
                float* a = &red[(p * 4 + mt) * 324 + n * 20 + quad * 4];
                f32x4 v = *(f32x4*)a;
                *(f32x4*)a = v + acc2[mt];
            }
        }
        __syncthreads();   // S6

        // ---- reduce2: owners -> h2 into LDS ----
        if (w < 4 && s >= 1) {
            const int mt = m >> 4, qm = m & 15;
            float g4[4];
            #pragma unroll
            for (int g = 0; g < 4; ++g) {
                float sum = bias2[g];
                #pragma unroll
                for (int pp = 0; pp < 8; ++pp)
                    sum += red[(pp * 4 + mt) * 324 + (il * 4 + g) * 20 + qm];
                g4[g] = sum;
            }
            float ig = sigm(g4[0]), fg = sigm(g4[1]);
            float gg = tanhf(g4[2]), og = sigm(g4[3]);
            c2 = fg * c2 + ig * gg;
            hbuf2[m * 4 + il] = (f16)(og * tanhf(c2));
        }
        __syncthreads();   // S7: hbuf2 ready

        // ---- wave 9: coalesced h2 store + tag publish ----
        if (w == 9 && s >= 1) {
            uint2 v = *(const uint2*)&hbuf2[lane * 4];
            st_cg8(ring2 + (size_t)((s + 1) & 1) * FRAME + oct4 * 512 + lane * 8 + coff, v);
            VM_DRAIN();
            if (lane == 0) tag_pub(tagB + bid, (unsigned)(s + 1));
        }
    }
    // final h2^{(511)} is in ring2 frame 1
}

// ---------------------------------------------------------------------------
// out[b] = dot(h2[b, :], fc_w) + fc_b.  h2 in octet layout.
// ---------------------------------------------------------------------------
__global__ void fc_kernel(const f16* __restrict__ h2f,
                          const float* __restrict__ fcw,
                          const float* __restrict__ fcb,
                          float* __restrict__ out) {
    __shared__ float red[256];
    const int tid = threadIdx.x;
    const int b = tid >> 2, q = tid & 3;
    float s = 0.f;
    for (int oct = q * 32; oct < (q + 1) * 32; ++oct) {
        f16x8 v = *(const f16x8*)(h2f + oct * 512 + b * 8);
        #pragma unroll
        for (int j = 0; j < 8; ++j)
            s = fmaf((float)v[j], fcw[oct * 8 + j], s);
    }
    red[tid] = s;
    __syncthreads();
    if (q == 0)
        out[b] = red[tid] + red[tid + 1] + red[tid + 2] + red[tid + 3] + fcb[0];
}

// ---------------------------------------------------------------------------
extern "C" void kernel_launch(void* const* d_in, const int* in_sizes, int n_in,
                              void* d_out, int out_size, void* d_ws, size_t ws_size,
                              hipStream_t stream) {
    const float* x    = (const float*)d_in[0];
    const float* Wih0 = (const float*)d_in[1];
    const float* Whh0 = (const float*)d_in[2];
    const float* bih0 = (const float*)d_in[3];
    const float* bhh0 = (const float*)d_in[4];
    const float* Wih1 = (const float*)d_in[5];
    const float* Whh1 = (const float*)d_in[6];
    const float* bih1 = (const float*)d_in[7];
    const float* bhh1 = (const float*)d_in[8];
    const float* fcw  = (const float*)d_in[9];
    const float* fcb  = (const float*)d_in[10];
    float* out = (float*)d_out;

    // workspace (halfs): xP | Wc0 | Wh0 | Wc1 | Wh1 | ring1 | ring2 | tags
    f16* xPd   = (f16*)d_ws;
    f16* Wc0   = xPd + (size_t)TDIM * BDIM * KIN;
    f16* Wh0   = Wc0 + (size_t)4 * HDIM * KIN;
    f16* Wc1   = Wh0 + (size_t)4 * HDIM * HDIM;
    f16* Wh1   = Wc1 + (size_t)4 * HDIM * HDIM;
    f16* ring1 = Wh1 + (size_t)4 * HDIM * HDIM;
    f16* ring2 = ring1 + 2 * FRAME;
    unsigned* tagA = (unsigned*)(ring2 + 2 * FRAME);
    unsigned* tagB = tagA + 512;      // 2 KB apart from tagA

    hipMemsetAsync(tagA, 0, 4096, stream);
    {
        int n2 = 4 * HDIM * KIN / 2;
        cvt_w<<<dim3((n2 + 255) / 256), dim3(256), 0, stream>>>(Wih0, Wc0, n2);
        n2 = 4 * HDIM * HDIM / 2;
        cvt_w<<<dim3((n2 + 255) / 256), dim3(256), 0, stream>>>(Whh0, Wh0, n2);
        cvt_w<<<dim3((n2 + 255) / 256), dim3(256), 0, stream>>>(Whh1, Wh1, n2);
        cvt_w<<<dim3((n2 + 255) / 256), dim3(256), 0, stream>>>(Wih1, Wc1, n2);
    }
    {
        int np = TDIM * BDIM * (KIN / 2);
        cvt_x<<<dim3((np + 255) / 256), dim3(256), 0, stream>>>(x, xPd);
    }

    void* args[13];
    args[0]  = (void*)&xPd;
    args[1]  = (void*)&Wc0;
    args[2]  = (void*)&Wh0;
    args[3]  = (void*)&bih0;
    args[4]  = (void*)&bhh0;
    args[5]  = (void*)&Wc1;
    args[6]  = (void*)&Wh1;
    args[7]  = (void*)&bih1;
    args[8]  = (void*)&bhh1;
    args[9]  = (void*)&ring1;
    args[10] = (void*)&ring2;
    args[11] = (void*)&tagA;
    args[12] = (void*)&tagB;
    hipLaunchCooperativeKernel(reinterpret_cast<void*>(lstm_fused), dim3(NBLK), dim3(NTHR),
                               args, 0, stream);

    fc_kernel<<<dim3(1), dim3(256), 0, stream>>>(ring2 + FRAME, fcw, fcb, out);
}